// Round 11
// baseline (14.524 us; speedup 1.0000x reference)
//
#include <hip/hip_runtime.h>
#include <math.h>

namespace {

typedef _Float16 f16;
typedef _Float16 f16x4 __attribute__((ext_vector_type(4)));
typedef _Float16 f16x8 __attribute__((ext_vector_type(8)));
typedef float    f32x4 __attribute__((ext_vector_type(4)));

constexpr int D  = 32;
constexpr int H  = 128;
constexpr int S1 = 40;    // W1T / vbuf stride (f16): 20dw rows -> even banks, b128-min (free)
constexpr int S2 = 152;   // W2T / hbuf/rbuf stride (f16): 76dw rows -> b128-min (free)
constexpr int THREADS = 256;   // 4 waves
constexpr int BPB = 64;        // 16 batch rows per wave

__device__ __forceinline__ float fast_tanh(float z) {
  float e = __expf(2.0f * z);
  return 1.0f - 2.0f * __builtin_amdgcn_rcpf(e + 1.0f);
}

__device__ __forceinline__ f32x4 mfma16(f16x8 a, f16x8 b, f32x4 c) {
  return __builtin_amdgcn_mfma_f32_16x16x32_f16(a, b, c, 0, 0, 0);
}

__device__ __forceinline__ f16x8 cvt8(float4 a, float4 b) {
  f16x8 r;
  r[0]=(f16)a.x; r[1]=(f16)a.y; r[2]=(f16)a.z; r[3]=(f16)a.w;
  r[4]=(f16)b.x; r[5]=(f16)b.y; r[6]=(f16)b.z; r[7]=(f16)b.w;
  return r;
}

// R7 (10.4us) is the local optimum: R8 (pair-split barriers), R9 (all-global
// frags), R10 (K16 chaining) all lost. This round changes ONE thing vs R7:
// natural-orientation A-frags (M: W2 rows, G: W1 rows) load straight from
// global as contiguous float4 pairs (L2-resident, coalesced) instead of being
// LDS-staged — the only R9/R10 component that was plausibly profitable.
// Transposed operands (Z: W1T, S/D: W2T) stay LDS-staged (R9 proved 8x-scalar
// global loads for those are a loss). LDS 84->64KB, staging ops -40%.
__global__ __launch_bounds__(THREADS, 1) void fpe_r11(
    const float* __restrict__ xg, const float* __restrict__ tg,
    const float* __restrict__ betag, const float* __restrict__ W1g,
    const float* __restrict__ b1g, const float* __restrict__ W2g,
    const float* __restrict__ b2g, float* __restrict__ out, int Btot)
{
  __shared__ alignas(16) f16 W1T[H * S1];       // [k_h][i]: A of Z
  __shared__ alignas(16) f16 W2T[D * S2];       // [j][k_h]: A of S/D
  __shared__ alignas(16) float cks[H];          // c_k = sum_j W1[j,k] W2[k,j]
  __shared__ alignas(16) f16 hbuf[4][16 * S2];  // per wave: h, then q (reused)
  __shared__ alignas(16) f16 rbuf[4][16 * S2];  // per wave: r = (1-h^2).*W1[32,:]
  __shared__ alignas(16) f16 vbuf[4][16 * S1];  // per wave: v = 2s + x

  const int tid = threadIdx.x;

  // ---- stage transposed weights only (4 scalar f16 writes per float4 chunk)
  for (int n4 = tid; n4 < (D * H) / 4; n4 += THREADS) {
    float4 w = ((const float4*)W1g)[n4];        // W1[i][k..k+3], i<32
    int flat = n4 * 4, i = flat >> 7, k = flat & 127;
    W1T[(k + 0) * S1 + i] = (f16)w.x;
    W1T[(k + 1) * S1 + i] = (f16)w.y;
    W1T[(k + 2) * S1 + i] = (f16)w.z;
    W1T[(k + 3) * S1 + i] = (f16)w.w;
  }
  for (int n4 = tid; n4 < (H * D) / 4; n4 += THREADS) {
    float4 w = ((const float4*)W2g)[n4];        // W2[k][j..j+3]
    int flat = n4 * 4, k = flat >> 5, j = flat & 31;
    W2T[(j + 0) * S2 + k] = (f16)w.x;
    W2T[(j + 1) * S2 + k] = (f16)w.y;
    W2T[(j + 2) * S2 + k] = (f16)w.z;
    W2T[(j + 3) * S2 + k] = (f16)w.w;
  }
  __syncthreads();

  if (tid < H) {                                // c_k: LDS W1T row x global W2 row
    const float4* w2r = (const float4*)(W2g + tid * D);
    float c = 0.f;
    #pragma unroll
    for (int q = 0; q < 4; ++q) {
      f16x8 a = *(const f16x8*)&W1T[tid * S1 + 8 * q];
      float4 wA = w2r[2 * q], wB = w2r[2 * q + 1];
      c += (float)a[0]*wA.x + (float)a[1]*wA.y + (float)a[2]*wA.z + (float)a[3]*wA.w
         + (float)a[4]*wB.x + (float)a[5]*wB.y + (float)a[6]*wB.z + (float)a[7]*wB.w;
    }
    cks[tid] = c;
  }
  __syncthreads();

  const int wv  = tid >> 6;
  const int ln  = tid & 63;
  const int col = ln & 15;       // batch column
  const int g4  = ln >> 4;       // 16-lane group
  const int b0  = blockIdx.x * BPB + wv * 16;
  if (b0 >= Btot) return;
  const int batch = min(b0 + col, Btot - 1);

  f16* hb = hbuf[wv];
  f16* rb = rbuf[wv];
  f16* vb = vbuf[wv];

  // ---- per-element loads
  const float* xrow = xg + (size_t)batch * D;
  const float4 xk0 = *(const float4*)(xrow + 8 * g4);       // B-frag of X^T
  const float4 xk1 = *(const float4*)(xrow + 8 * g4 + 4);
  const float4 xc0 = *(const float4*)(xrow + 4 * g4);       // C-layout x, om=0
  const float4 xc1 = *(const float4*)(xrow + 16 + 4 * g4);  // om=1
  const float tval  = tg[batch];
  const float hbeta = 0.5f * betag[batch];

  const f16x8 bx = cvt8(xk0, xk1);

  // ===== Z: z = W1^T x + b1 + t*W1[32,:]; h = tanh z; h,r -> LDS
  float hC[8][4];
  #pragma unroll 2
  for (int hm = 0; hm < 8; ++hm) {
    f16x8 a = *(const f16x8*)&W1T[(16 * hm + col) * S1 + 8 * g4];
    f32x4 z = mfma16(a, bx, f32x4{0.f, 0.f, 0.f, 0.f});
    const float4 b1v = *(const float4*)(b1g + 16 * hm + 4 * g4);
    const float4 wtv = *(const float4*)(W1g + D * H + 16 * hm + 4 * g4);
    f16x4 hv, rv;
    #pragma unroll
    for (int r = 0; r < 4; ++r) {
      float zz = z[r] + ((const float*)&b1v)[r] + ((const float*)&wtv)[r] * tval;
      float hh = fast_tanh(zz);
      hC[hm][r] = hh;
      hv[r] = (f16)hh;
      rv[r] = (f16)(fmaf(-hh, hh, 1.0f) * ((const float*)&wtv)[r]);
    }
    *(f16x4*)&hb[col * S2 + 16 * hm + 4 * g4] = hv;
    *(f16x4*)&rb[col * S2 + 16 * hm + 4 * g4] = rv;
  }

  // ===== S/D: s = W2^T h + b2 ; dsdt = W2^T r  (K=128)
  f32x4 sT[2] = {{0.f,0.f,0.f,0.f}, {0.f,0.f,0.f,0.f}};
  f32x4 dT[2] = {{0.f,0.f,0.f,0.f}, {0.f,0.f,0.f,0.f}};
  #pragma unroll 2
  for (int ks = 0; ks < 4; ++ks) {
    f16x8 hvf = *(const f16x8*)&hb[col * S2 + 32 * ks + 8 * g4];
    f16x8 rvf = *(const f16x8*)&rb[col * S2 + 32 * ks + 8 * g4];
    #pragma unroll
    for (int om = 0; om < 2; ++om) {
      f16x8 a = *(const f16x8*)&W2T[(16 * om + col) * S2 + 32 * ks + 8 * g4];
      sT[om] = mfma16(a, hvf, sT[om]);
      dT[om] = mfma16(a, rvf, dT[om]);
    }
  }
  // s += b2 ; v = 2s + x -> vbuf
  #pragma unroll
  for (int om = 0; om < 2; ++om) {
    const float4 b2v = *(const float4*)(b2g + 16 * om + 4 * g4);
    const float4 xcv = om ? xc1 : xc0;
    f16x4 vv;
    #pragma unroll
    for (int r = 0; r < 4; ++r) {
      sT[om][r] += ((const float*)&b2v)[r];
      vv[r] = (f16)fmaf(2.0f, sT[om][r], ((const float*)&xcv)[r]);
    }
    *(f16x4*)&vb[col * S1 + 16 * om + 4 * g4] = vv;
  }

  // ===== M: m = W2 v (K=32); q = (1-h^2).*(m - 2c.*h) -> hbuf (h dead)
  {
    f16x8 bv = *(const f16x8*)&vb[col * S1 + 8 * g4];
    #pragma unroll 2
    for (int hm = 0; hm < 8; ++hm) {
      const float* ap = W2g + (16 * hm + col) * D + 8 * g4;   // contiguous row
      f16x8 af = cvt8(*(const float4*)ap, *(const float4*)(ap + 4));
      f32x4 m = mfma16(af, bv, f32x4{0.f, 0.f, 0.f, 0.f});
      const float4 cv = *(const float4*)&cks[16 * hm + 4 * g4];
      f16x4 qv;
      #pragma unroll
      for (int r = 0; r < 4; ++r) {
        float hh = hC[hm][r];
        float mm = fmaf(-2.0f * ((const float*)&cv)[r], hh, m[r]);
        qv[r] = (f16)(fmaf(-hh, hh, 1.0f) * mm);
      }
      *(f16x4*)&hb[col * S2 + 16 * hm + 4 * g4] = qv;
    }
  }

  // ===== G: grad-part = W1x q (K=128)
  f32x4 gT[2] = {{0.f,0.f,0.f,0.f}, {0.f,0.f,0.f,0.f}};
  #pragma unroll 2
  for (int ks = 0; ks < 4; ++ks) {
    f16x8 q8 = *(const f16x8*)&hb[col * S2 + 32 * ks + 8 * g4];
    #pragma unroll
    for (int om = 0; om < 2; ++om) {
      const float* ap = W1g + (16 * om + col) * H + 32 * ks + 8 * g4;  // contiguous
      f16x8 af = cvt8(*(const float4*)ap, *(const float4*)(ap + 4));
      gT[om] = mfma16(af, q8, gT[om]);
    }
  }

  // ===== resid = dsdt - hb*(s + grad); L1 mean; reduce 4 lane-groups
  float acc = 0.f;
  #pragma unroll
  for (int om = 0; om < 2; ++om)
    #pragma unroll
    for (int r = 0; r < 4; ++r)
      acc += fabsf(dT[om][r] - hbeta * (sT[om][r] + gT[om][r]));
  acc += __shfl_xor(acc, 16);
  acc += __shfl_xor(acc, 32);
  if (ln < 16 && (b0 + ln) < Btot) out[b0 + ln] = acc * (1.0f / 32.0f);
}

} // namespace

extern "C" void kernel_launch(void* const* d_in, const int* in_sizes, int n_in,
                              void* d_out, int out_size, void* d_ws, size_t ws_size,
                              hipStream_t stream) {
  const float* x    = (const float*)d_in[0];
  const float* t    = (const float*)d_in[1];
  const float* beta = (const float*)d_in[2];
  const float* W1   = (const float*)d_in[3];
  const float* b1   = (const float*)d_in[4];
  const float* W2   = (const float*)d_in[5];
  const float* b2   = (const float*)d_in[6];
  float* out = (float*)d_out;

  const int Btot = in_sizes[1];  // t is [B,1]
  const int grid = (Btot + BPB - 1) / BPB;
  hipLaunchKernelGGL(fpe_r11, dim3(grid), dim3(THREADS), 0, stream,
                     x, t, beta, W1, b1, W2, b2, out, Btot);
}

// Round 12
// 10.713 us; speedup vs baseline: 1.3558x; 1.3558x over previous
//
#include <hip/hip_runtime.h>
#include <math.h>

namespace {

typedef _Float16 f16;
typedef _Float16 f16x8 __attribute__((ext_vector_type(8)));
typedef _Float16 f16x4 __attribute__((ext_vector_type(4)));
typedef float    f32x4 __attribute__((ext_vector_type(4)));

constexpr int D  = 32;
constexpr int H  = 128;
constexpr int S1 = 40;    // f16 row stride for K=32 operands  (80 B, mult of 16)
constexpr int S2 = 136;   // f16 row stride for K=128 operands (272 B, mult of 16)
constexpr int THREADS = 256;   // 4 waves
constexpr int BPW = 16;        // batch rows per wave (= MFMA N)
constexpr int BPB = 64;        // batch rows per block

__device__ __forceinline__ float fast_tanh(float z) {
  float e = __expf(2.0f * z);
  return 1.0f - 2.0f * __builtin_amdgcn_rcpf(e + 1.0f);
}

__device__ __forceinline__ f32x4 mfma16(f16x8 a, f16x8 b, f32x4 c) {
  return __builtin_amdgcn_mfma_f32_16x16x32_f16(a, b, c, 0, 0, 0);
}

// R7 restored (10.4us, the measured optimum; R8-R11 structural variants all
// lost: pair-split barriers 11.7, global transposed frags 14.1, K16 chaining
// 12.4, global natural frags 14.5 — at 1 wave/SIMD every extra issue or
// exposed-latency op lengthens the single serial wave chain).
// ONE change vs R7: c_k is computed from GLOBAL W1/W2 (independent of LDS
// staging, overlaps with it) instead of from staged LDS between two barriers
// -> the serial c_k phase and one barrier are eliminated.
__global__ __launch_bounds__(THREADS, 1) void fpe_mfma(
    const float* __restrict__ xg, const float* __restrict__ tg,
    const float* __restrict__ betag, const float* __restrict__ W1g,
    const float* __restrict__ b1g, const float* __restrict__ W2g,
    const float* __restrict__ b2g, float* __restrict__ out, int Btot)
{
  __shared__ alignas(16) f16 W1T[H * S1];       // [h][i]: W1^T x-part, A of Z
  __shared__ alignas(16) f16 W1X[D * S2];       // [j][k]: W1 x-part,   A of G
  __shared__ alignas(16) f16 W2R[H * S1];       // [k][j]: W2,          A of M
  __shared__ alignas(16) f16 W2T[D * S2];       // [j][k]: W2^T,        A of S/dsdt
  __shared__ alignas(16) float b1s[H];
  __shared__ alignas(16) float cks[H];          // c_k = sum_j W1[j,k] W2[k,j]
  __shared__ alignas(16) float b2s[D];
  __shared__ alignas(16) f16  w132h[H];         // W1[32,k] (t-row)
  __shared__ alignas(16) f16 pbuf[4][BPW * S2]; // per wave: h, then q
  __shared__ alignas(16) f16 vbuf[4][BPW * S1]; // per wave: v

  const int tid = threadIdx.x;

  // ---- c_k from global (independent of staging; overlaps with it)
  if (tid < H) {
    const float* w2row = W2g + tid * D;
    float c0 = 0.f, c1 = 0.f, c2 = 0.f, c3 = 0.f;
    #pragma unroll
    for (int j = 0; j < D; j += 4) {
      c0 = fmaf(W1g[(j + 0) * H + tid], w2row[j + 0], c0);
      c1 = fmaf(W1g[(j + 1) * H + tid], w2row[j + 1], c1);
      c2 = fmaf(W1g[(j + 2) * H + tid], w2row[j + 2], c2);
      c3 = fmaf(W1g[(j + 3) * H + tid], w2row[j + 3], c3);
    }
    cks[tid] = (c0 + c1) + (c2 + c3);
  }

  // ---- stage weights once per block (f16, both orientations)
  for (int n = tid; n < D * H; n += THREADS) {
    int i = n >> 7, k = n & (H - 1);            // W1[i][k], i<32
    f16 w = (f16)W1g[n];
    W1T[k * S1 + i] = w;
    W1X[i * S2 + k] = w;
  }
  for (int n = tid; n < H * D; n += THREADS) {
    int k = n >> 5, j = n & (D - 1);            // W2[k][j]
    f16 w = (f16)W2g[n];
    W2R[k * S1 + j] = w;
    W2T[j * S2 + k] = w;
  }
  if (tid < H) { w132h[tid] = (f16)W1g[D * H + tid]; b1s[tid] = b1g[tid]; }
  if (tid < D) b2s[tid] = b2g[tid];
  __syncthreads();

  const int wv  = tid >> 6;
  const int ln  = tid & 63;
  const int col = ln & 15;                      // batch column
  const int g4  = ln >> 4;                      // 16-lane group
  const int b0  = blockIdx.x * BPB + wv * BPW;
  if (b0 >= Btot) return;
  const int batch = min(b0 + col, Btot - 1);

  f16* pb = pbuf[wv];
  f16* vb = vbuf[wv];

  // ---- per-element global loads (issue all up front)
  const float* xrow = xg + (size_t)batch * D;
  const float4 xk0 = *(const float4*)(xrow + 8 * g4);       // B-frag of X^T
  const float4 xk1 = *(const float4*)(xrow + 8 * g4 + 4);
  const float4 xc0 = *(const float4*)(xrow + 4 * g4);       // C-layout x, om=0
  const float4 xc1 = *(const float4*)(xrow + 16 + 4 * g4);  // om=1
  const float tval = tg[batch];
  const float hb   = 0.5f * betag[batch];

  f16x8 bx;
  bx[0] = (f16)xk0.x; bx[1] = (f16)xk0.y; bx[2] = (f16)xk0.z; bx[3] = (f16)xk0.w;
  bx[4] = (f16)xk1.x; bx[5] = (f16)xk1.y; bx[6] = (f16)xk1.z; bx[7] = (f16)xk1.w;

  // ===== Z = W1^T X^T (K=32) + rank-1 t + b1 -> h (kept in C-frags + LDS f16)
  float hC[8][4];
  #pragma unroll
  for (int hm = 0; hm < 8; ++hm) {
    f16x8 a = *(const f16x8*)&W1T[(16 * hm + col) * S1 + 8 * g4];
    f32x4 zero = {0.f, 0.f, 0.f, 0.f};
    f32x4 z = mfma16(a, bx, zero);
    float4 b1v = *(const float4*)&b1s[16 * hm + 4 * g4];
    f16x4 wtv  = *(const f16x4*)&w132h[16 * hm + 4 * g4];
    f16x4 hv;
    #pragma unroll
    for (int r = 0; r < 4; ++r) {
      float zz = z[r] + ((const float*)&b1v)[r] + (float)wtv[r] * tval;
      float hh = fast_tanh(zz);
      hC[hm][r] = hh;
      hv[r] = (f16)hh;
    }
    *(f16x4*)&pb[col * S2 + 16 * hm + 4 * g4] = hv;
  }

  // ===== S^T = W2^T H^T + b2 ; dsdt^T = W2^T R^T, R = g .* W1[32,:] (K=128)
  f32x4 sT[2], dT[2];
  sT[0] = {0.f,0.f,0.f,0.f}; sT[1] = {0.f,0.f,0.f,0.f};
  dT[0] = {0.f,0.f,0.f,0.f}; dT[1] = {0.f,0.f,0.f,0.f};
  #pragma unroll
  for (int ks = 0; ks < 4; ++ks) {
    f16x8 hvf = *(const f16x8*)&pb[col * S2 + 32 * ks + 8 * g4];
    f16x8 wv8 = *(const f16x8*)&w132h[32 * ks + 8 * g4];
    f16x8 rv;
    #pragma unroll
    for (int r = 0; r < 8; ++r) {
      float hf = (float)hvf[r];
      float gg = fmaf(-hf, hf, 1.0f);
      rv[r] = (f16)(gg * (float)wv8[r]);
    }
    #pragma unroll
    for (int om = 0; om < 2; ++om) {
      f16x8 a = *(const f16x8*)&W2T[(16 * om + col) * S2 + 32 * ks + 8 * g4];
      sT[om] = mfma16(a, hvf, sT[om]);
      dT[om] = mfma16(a, rv,  dT[om]);
    }
  }
  // s += b2 ; v = 2s + x -> vbuf (f16)
  #pragma unroll
  for (int om = 0; om < 2; ++om) {
    float4 b2v = *(const float4*)&b2s[16 * om + 4 * g4];
    float4 xcv = om ? xc1 : xc0;
    f16x4 vv;
    #pragma unroll
    for (int r = 0; r < 4; ++r) {
      sT[om][r] += ((const float*)&b2v)[r];
      vv[r] = (f16)fmaf(2.0f, sT[om][r], ((const float*)&xcv)[r]);
    }
    *(f16x4*)&vb[col * S1 + 16 * om + 4 * g4] = vv;
  }

  // ===== M^T = W2 V^T (K=32) ; Q = g .* (M - 2 c .* H) -> pbuf (overwrite h)
  {
    f16x8 bv = *(const f16x8*)&vb[col * S1 + 8 * g4];
    #pragma unroll
    for (int hm = 0; hm < 8; ++hm) {
      f16x8 a = *(const f16x8*)&W2R[(16 * hm + col) * S1 + 8 * g4];
      f32x4 zero = {0.f, 0.f, 0.f, 0.f};
      f32x4 m = mfma16(a, bv, zero);
      float4 cv = *(const float4*)&cks[16 * hm + 4 * g4];
      f16x4 qv;
      #pragma unroll
      for (int r = 0; r < 4; ++r) {
        float hh = hC[hm][r];
        float gg = fmaf(-hh, hh, 1.0f);
        float mm = fmaf(-2.0f * ((const float*)&cv)[r], hh, m[r]);
        qv[r] = (f16)(gg * mm);
      }
      *(f16x4*)&pb[col * S2 + 16 * hm + 4 * g4] = qv;
    }
  }

  // ===== G^T = W1x Q^T (K=128)
  f32x4 gT[2];
  gT[0] = {0.f,0.f,0.f,0.f}; gT[1] = {0.f,0.f,0.f,0.f};
  #pragma unroll
  for (int ks = 0; ks < 4; ++ks) {
    f16x8 q8 = *(const f16x8*)&pb[col * S2 + 32 * ks + 8 * g4];
    #pragma unroll
    for (int om = 0; om < 2; ++om) {
      f16x8 a = *(const f16x8*)&W1X[(16 * om + col) * S2 + 32 * ks + 8 * g4];
      gT[om] = mfma16(a, q8, gT[om]);
    }
  }

  // ===== resid = dsdt - hb*(s + G) ; L1 mean over j ; reduce 4 lane-groups
  float acc = 0.f;
  #pragma unroll
  for (int om = 0; om < 2; ++om)
    #pragma unroll
    for (int r = 0; r < 4; ++r)
      acc += fabsf(dT[om][r] - hb * (sT[om][r] + gT[om][r]));
  acc += __shfl_xor(acc, 16);
  acc += __shfl_xor(acc, 32);
  if (ln < BPW && (b0 + ln) < Btot) out[b0 + ln] = acc * (1.0f / 32.0f);
}

} // namespace

extern "C" void kernel_launch(void* const* d_in, const int* in_sizes, int n_in,
                              void* d_out, int out_size, void* d_ws, size_t ws_size,
                              hipStream_t stream) {
  const float* x    = (const float*)d_in[0];
  const float* t    = (const float*)d_in[1];
  const float* beta = (const float*)d_in[2];
  const float* W1   = (const float*)d_in[3];
  const float* b1   = (const float*)d_in[4];
  const float* W2   = (const float*)d_in[5];
  const float* b2   = (const float*)d_in[6];
  float* out = (float*)d_out;

  const int Btot = in_sizes[1];  // t is [B,1]
  const int grid = (Btot + BPB - 1) / BPB;
  hipLaunchKernelGGL(fpe_mfma, dim3(grid), dim3(THREADS), 0, stream,
                     x, t, beta, W1, b1, W2, b2, out, Btot);
}

// Round 13
// 10.389 us; speedup vs baseline: 1.3980x; 1.0311x over previous
//
#include <hip/hip_runtime.h>
#include <math.h>

namespace {

typedef _Float16 f16;
typedef _Float16 f16x8 __attribute__((ext_vector_type(8)));
typedef _Float16 f16x4 __attribute__((ext_vector_type(4)));
typedef float    f32x4 __attribute__((ext_vector_type(4)));

constexpr int D  = 32;
constexpr int H  = 128;
constexpr int S1 = 40;    // f16 row stride for K=32 operands  (80 B)
constexpr int S2 = 136;   // f16 row stride for K=128 operands (272 B)
constexpr int THREADS = 256;   // 4 waves
constexpr int BPW = 16;        // batch rows per wave (= MFMA N)
constexpr int BPB = 64;        // batch rows per block

__device__ __forceinline__ float fast_tanh(float z) {
  float e = __expf(2.0f * z);
  return 1.0f - 2.0f * __builtin_amdgcn_rcpf(e + 1.0f);
}

__device__ __forceinline__ f32x4 mfma16(f16x8 a, f16x8 b, f32x4 c) {
  return __builtin_amdgcn_mfma_f32_16x16x32_f16(a, b, c, 0, 0, 0);
}

// R7/R12 compute chain (measured optimum: R8-R11 restructurings all lost).
// R13 changes ONLY the staging phase: each thread owns a 4x4 register tile
// per weight matrix -- 4 float4 loads, then BOTH orientations written as
// f16x4 ds_write_b64 (natural rows direct, transposed rows via in-register
// tile transpose). Lane mapping (it/jt fast) makes every b64 write instr
// spread over 16 bank-pair starts -> 4-way (~free, m136). Per-thread staging
// drops ~200 issues -> ~60, LDS conflict-slots ~91 -> ~25.
__global__ __launch_bounds__(THREADS, 1) void fpe_mfma(
    const float* __restrict__ xg, const float* __restrict__ tg,
    const float* __restrict__ betag, const float* __restrict__ W1g,
    const float* __restrict__ b1g, const float* __restrict__ W2g,
    const float* __restrict__ b2g, float* __restrict__ out, int Btot)
{
  __shared__ alignas(16) f16 W1T[H * S1];       // [k][i]: W1^T x-part, A of Z
  __shared__ alignas(16) f16 W1X[D * S2];       // [i][k]: W1 x-part,   A of G
  __shared__ alignas(16) f16 W2R[H * S1];       // [k][j]: W2,          A of M
  __shared__ alignas(16) f16 W2T[D * S2];       // [j][k]: W2^T,        A of S/dsdt
  __shared__ alignas(16) float b1s[H];
  __shared__ alignas(16) float cks[H];          // c_k = sum_j W1[j,k] W2[k,j]
  __shared__ alignas(16) float b2s[D];
  __shared__ alignas(16) f16  w132h[H];         // W1[32,k] (t-row)
  __shared__ alignas(16) f16 pbuf[4][BPW * S2]; // per wave: h, then q
  __shared__ alignas(16) f16 vbuf[4][BPW * S1]; // per wave: v

  const int tid = threadIdx.x;

  // ---- c_k from global (independent of staging; overlaps with it)
  if (tid < H) {
    const float* w2row = W2g + tid * D;
    float c0 = 0.f, c1 = 0.f, c2 = 0.f, c3 = 0.f;
    #pragma unroll
    for (int j = 0; j < D; j += 4) {
      c0 = fmaf(W1g[(j + 0) * H + tid], w2row[j + 0], c0);
      c1 = fmaf(W1g[(j + 1) * H + tid], w2row[j + 1], c1);
      c2 = fmaf(W1g[(j + 2) * H + tid], w2row[j + 2], c2);
      c3 = fmaf(W1g[(j + 3) * H + tid], w2row[j + 3], c3);
    }
    cks[tid] = (c0 + c1) + (c2 + c3);
  }

  // ---- staging: 4x4 register tiles, both orientations, all-b64 writes
  {
    // W1 (x-part, 32x128): tile (it, kt); it fast across lanes
    const int it = tid & 7;         // i-tile 0..7  (i0 = 4*it)
    const int kt = tid >> 3;        // k-tile 0..31 (k0 = 4*kt)
    float4 w1r[4];
    #pragma unroll
    for (int r = 0; r < 4; ++r)
      w1r[r] = *(const float4*)(W1g + (4 * it + r) * H + 4 * kt);
    #pragma unroll
    for (int r = 0; r < 4; ++r) {   // natural rows -> W1X[i][k..k+3]
      const float* wr = (const float*)&w1r[r];
      f16x4 v = {(f16)wr[0], (f16)wr[1], (f16)wr[2], (f16)wr[3]};
      *(f16x4*)&W1X[(4 * it + r) * S2 + 4 * kt] = v;
    }
    #pragma unroll
    for (int c = 0; c < 4; ++c) {   // transposed rows -> W1T[k][i..i+3]
      f16x4 v = {(f16)((const float*)&w1r[0])[c], (f16)((const float*)&w1r[1])[c],
                 (f16)((const float*)&w1r[2])[c], (f16)((const float*)&w1r[3])[c]};
      *(f16x4*)&W1T[(4 * kt + c) * S1 + 4 * it] = v;
    }
    // W2 (128x32): tile (kt2, jt); jt fast across lanes
    const int jt  = tid & 7;        // j-tile 0..7  (j0 = 4*jt)
    const int kt2 = tid >> 3;       // k-tile 0..31 (k0 = 4*kt2)
    float4 w2r[4];
    #pragma unroll
    for (int r = 0; r < 4; ++r)
      w2r[r] = *(const float4*)(W2g + (4 * kt2 + r) * D + 4 * jt);
    #pragma unroll
    for (int r = 0; r < 4; ++r) {   // natural rows -> W2R[k][j..j+3]
      const float* wr = (const float*)&w2r[r];
      f16x4 v = {(f16)wr[0], (f16)wr[1], (f16)wr[2], (f16)wr[3]};
      *(f16x4*)&W2R[(4 * kt2 + r) * S1 + 4 * jt] = v;
    }
    #pragma unroll
    for (int c = 0; c < 4; ++c) {   // transposed rows -> W2T[j][k..k+3]
      f16x4 v = {(f16)((const float*)&w2r[0])[c], (f16)((const float*)&w2r[1])[c],
                 (f16)((const float*)&w2r[2])[c], (f16)((const float*)&w2r[3])[c]};
      *(f16x4*)&W2T[(4 * jt + c) * S2 + 4 * kt2] = v;
    }
  }
  if (tid < H) { w132h[tid] = (f16)W1g[D * H + tid]; b1s[tid] = b1g[tid]; }
  if (tid < D) b2s[tid] = b2g[tid];
  __syncthreads();

  const int wv  = tid >> 6;
  const int ln  = tid & 63;
  const int col = ln & 15;                      // batch column
  const int g4  = ln >> 4;                      // 16-lane group
  const int b0  = blockIdx.x * BPB + wv * BPW;
  if (b0 >= Btot) return;
  const int batch = min(b0 + col, Btot - 1);

  f16* pb = pbuf[wv];
  f16* vb = vbuf[wv];

  // ---- per-element global loads (issue all up front)
  const float* xrow = xg + (size_t)batch * D;
  const float4 xk0 = *(const float4*)(xrow + 8 * g4);       // B-frag of X^T
  const float4 xk1 = *(const float4*)(xrow + 8 * g4 + 4);
  const float4 xc0 = *(const float4*)(xrow + 4 * g4);       // C-layout x, om=0
  const float4 xc1 = *(const float4*)(xrow + 16 + 4 * g4);  // om=1
  const float tval = tg[batch];
  const float hb   = 0.5f * betag[batch];

  f16x8 bx;
  bx[0] = (f16)xk0.x; bx[1] = (f16)xk0.y; bx[2] = (f16)xk0.z; bx[3] = (f16)xk0.w;
  bx[4] = (f16)xk1.x; bx[5] = (f16)xk1.y; bx[6] = (f16)xk1.z; bx[7] = (f16)xk1.w;

  // ===== Z = W1^T X^T (K=32) + rank-1 t + b1 -> h (kept in C-frags + LDS f16)
  float hC[8][4];
  #pragma unroll
  for (int hm = 0; hm < 8; ++hm) {
    f16x8 a = *(const f16x8*)&W1T[(16 * hm + col) * S1 + 8 * g4];
    f32x4 zero = {0.f, 0.f, 0.f, 0.f};
    f32x4 z = mfma16(a, bx, zero);
    float4 b1v = *(const float4*)&b1s[16 * hm + 4 * g4];
    f16x4 wtv  = *(const f16x4*)&w132h[16 * hm + 4 * g4];
    f16x4 hv;
    #pragma unroll
    for (int r = 0; r < 4; ++r) {
      float zz = z[r] + ((const float*)&b1v)[r] + (float)wtv[r] * tval;
      float hh = fast_tanh(zz);
      hC[hm][r] = hh;
      hv[r] = (f16)hh;
    }
    *(f16x4*)&pb[col * S2 + 16 * hm + 4 * g4] = hv;
  }

  // ===== S^T = W2^T H^T + b2 ; dsdt^T = W2^T R^T, R = g .* W1[32,:] (K=128)
  f32x4 sT[2], dT[2];
  sT[0] = {0.f,0.f,0.f,0.f}; sT[1] = {0.f,0.f,0.f,0.f};
  dT[0] = {0.f,0.f,0.f,0.f}; dT[1] = {0.f,0.f,0.f,0.f};
  #pragma unroll
  for (int ks = 0; ks < 4; ++ks) {
    f16x8 hvf = *(const f16x8*)&pb[col * S2 + 32 * ks + 8 * g4];
    f16x8 wv8 = *(const f16x8*)&w132h[32 * ks + 8 * g4];
    f16x8 rv;
    #pragma unroll
    for (int r = 0; r < 8; ++r) {
      float hf = (float)hvf[r];
      float gg = fmaf(-hf, hf, 1.0f);
      rv[r] = (f16)(gg * (float)wv8[r]);
    }
    #pragma unroll
    for (int om = 0; om < 2; ++om) {
      f16x8 a = *(const f16x8*)&W2T[(16 * om + col) * S2 + 32 * ks + 8 * g4];
      sT[om] = mfma16(a, hvf, sT[om]);
      dT[om] = mfma16(a, rv,  dT[om]);
    }
  }
  // s += b2 ; v = 2s + x -> vbuf (f16)
  #pragma unroll
  for (int om = 0; om < 2; ++om) {
    float4 b2v = *(const float4*)&b2s[16 * om + 4 * g4];
    float4 xcv = om ? xc1 : xc0;
    f16x4 vv;
    #pragma unroll
    for (int r = 0; r < 4; ++r) {
      sT[om][r] += ((const float*)&b2v)[r];
      vv[r] = (f16)fmaf(2.0f, sT[om][r], ((const float*)&xcv)[r]);
    }
    *(f16x4*)&vb[col * S1 + 16 * om + 4 * g4] = vv;
  }

  // ===== M^T = W2 V^T (K=32) ; Q = g .* (M - 2 c .* H) -> pbuf (overwrite h)
  {
    f16x8 bv = *(const f16x8*)&vb[col * S1 + 8 * g4];
    #pragma unroll
    for (int hm = 0; hm < 8; ++hm) {
      f16x8 a = *(const f16x8*)&W2R[(16 * hm + col) * S1 + 8 * g4];
      f32x4 zero = {0.f, 0.f, 0.f, 0.f};
      f32x4 m = mfma16(a, bv, zero);
      float4 cv = *(const float4*)&cks[16 * hm + 4 * g4];
      f16x4 qv;
      #pragma unroll
      for (int r = 0; r < 4; ++r) {
        float hh = hC[hm][r];
        float gg = fmaf(-hh, hh, 1.0f);
        float mm = fmaf(-2.0f * ((const float*)&cv)[r], hh, m[r]);
        qv[r] = (f16)(gg * mm);
      }
      *(f16x4*)&pb[col * S2 + 16 * hm + 4 * g4] = qv;
    }
  }

  // ===== G^T = W1x Q^T (K=128)
  f32x4 gT[2];
  gT[0] = {0.f,0.f,0.f,0.f}; gT[1] = {0.f,0.f,0.f,0.f};
  #pragma unroll
  for (int ks = 0; ks < 4; ++ks) {
    f16x8 q8 = *(const f16x8*)&pb[col * S2 + 32 * ks + 8 * g4];
    #pragma unroll
    for (int om = 0; om < 2; ++om) {
      f16x8 a = *(const f16x8*)&W1X[(16 * om + col) * S2 + 32 * ks + 8 * g4];
      gT[om] = mfma16(a, q8, gT[om]);
    }
  }

  // ===== resid = dsdt - hb*(s + G) ; L1 mean over j ; reduce 4 lane-groups
  float acc = 0.f;
  #pragma unroll
  for (int om = 0; om < 2; ++om)
    #pragma unroll
    for (int r = 0; r < 4; ++r)
      acc += fabsf(dT[om][r] - hb * (sT[om][r] + gT[om][r]));
  acc += __shfl_xor(acc, 16);
  acc += __shfl_xor(acc, 32);
  if (ln < BPW && (b0 + ln) < Btot) out[b0 + ln] = acc * (1.0f / 32.0f);
}

} // namespace

extern "C" void kernel_launch(void* const* d_in, const int* in_sizes, int n_in,
                              void* d_out, int out_size, void* d_ws, size_t ws_size,
                              hipStream_t stream) {
  const float* x    = (const float*)d_in[0];
  const float* t    = (const float*)d_in[1];
  const float* beta = (const float*)d_in[2];
  const float* W1   = (const float*)d_in[3];
  const float* b1   = (const float*)d_in[4];
  const float* W2   = (const float*)d_in[5];
  const float* b2   = (const float*)d_in[6];
  float* out = (float*)d_out;

  const int Btot = in_sizes[1];  // t is [B,1]
  const int grid = (Btot + BPB - 1) / BPB;
  hipLaunchKernelGGL(fpe_mfma, dim3(grid), dim3(THREADS), 0, stream,
                     x, t, beta, W1, b1, W2, b2, out, Btot);
}